// Round 2
// baseline (499.408 us; speedup 1.0000x reference)
//
#include <hip/hip_runtime.h>
#include <hip/hip_bf16.h>

#define ALPHA 0.2f

constexpr int BN   = 4;
constexpr int NN   = 4096;
constexpr int FIN  = 256;
constexpr int FOUT = 128;
constexpr int NSPLIT = 4;   // reduction-axis split for partials (e-pass kernels)

typedef __attribute__((ext_vector_type(8))) short bf16x8;
typedef __attribute__((ext_vector_type(4))) float f32x4;

#define MFMA16(a, b, c) __builtin_amdgcn_mfma_f32_16x16x32_bf16((a), (b), (c), 0, 0, 0)

// ---------- split one fp32 octet into hi/lo bf16 granules (16B each) ----------
__device__ __forceinline__ void split8(const float* x, uint4& H, uint4& L) {
    ushort hb[8], lb[8];
    #pragma unroll
    for (int i = 0; i < 8; ++i) {
        float xv = x[i];
        __hip_bfloat16 hh = __float2bfloat16(xv);
        float hf = __bfloat162float(hh);
        __hip_bfloat16 lw = __float2bfloat16(xv - hf);
        hb[i] = reinterpret_cast<const ushort&>(hh);
        lb[i] = reinterpret_cast<const ushort&>(lw);
    }
    H = make_uint4((uint)hb[0] | ((uint)hb[1] << 16), (uint)hb[2] | ((uint)hb[3] << 16),
                   (uint)hb[4] | ((uint)hb[5] << 16), (uint)hb[6] | ((uint)hb[7] << 16));
    L = make_uint4((uint)lb[0] | ((uint)lb[1] << 16), (uint)lb[2] | ((uint)lb[3] << 16),
                   (uint)lb[4] | ((uint)lb[5] << 16), (uint)lb[6] | ((uint)lb[7] << 16));
}

// ---------- stage fp32 [ROWS][8<<KGSH] (row stride strideF) -> swizzled hi/lo bf16 LDS ----------
// LDS granule layout: granule g of row r stored at r*(1<<KGSH) + (g ^ (r&7))  [16B units]
template<int ROWS, int KGSH>
__device__ __forceinline__ void stage_split(const float* __restrict__ src, int strideF,
                                            ushort* hi, ushort* lo, int tid) {
    constexpr int KG = 1 << KGSH;
    #pragma unroll
    for (int idx = tid; idx < ROWS * KG; idx += 256) {
        int row = idx >> KGSH, g = idx & (KG - 1);
        const float4* p4 = reinterpret_cast<const float4*>(src + (size_t)row * strideF + g * 8);
        float4 u = p4[0], v = p4[1];
        float x[8] = {u.x, u.y, u.z, u.w, v.x, v.y, v.z, v.w};
        uint4 H, L;
        split8(x, H, L);
        int gran = (row << KGSH) + (g ^ (row & 7));
        reinterpret_cast<uint4*>(hi)[gran] = H;
        reinterpret_cast<uint4*>(lo)[gran] = L;
    }
}

// ---------- stage pre-split bf16 [ROWS][8<<KGSH] (row stride strideU ushorts) -> swizzled LDS ----------
template<int ROWS, int KGSH>
__device__ __forceinline__ void stage_copy(const ushort* __restrict__ src, int strideU,
                                           ushort* dst, int tid) {
    constexpr int KG = 1 << KGSH;
    #pragma unroll
    for (int idx = tid; idx < ROWS * KG; idx += 256) {
        int row = idx >> KGSH, g = idx & (KG - 1);
        uint4 vv = *reinterpret_cast<const uint4*>(src + (size_t)row * strideU + g * 8);
        reinterpret_cast<uint4*>(dst)[(row << KGSH) + (g ^ (row & 7))] = vv;
    }
}

// ---------- fragment read: row (rowbase + lane&15), k-granule kstep*4 + lane>>4 ----------
__device__ __forceinline__ bf16x8 frag16(const ushort* s, int rowbase, int kstep, int kgsh, int lane) {
    int r = rowbase + (lane & 15);
    int g = kstep * 4 + (lane >> 4);
    int gran = (r << kgsh) + (g ^ (r & 7));
    return *reinterpret_cast<const bf16x8*>(s + gran * 8);
}

// ---------------- K0: transpose + split W -> Wt_hi/Wt_lo [FOUT][FIN] bf16 ----------------
__global__ void k_prepW(const float* __restrict__ W, ushort* __restrict__ Wt_hi,
                        ushort* __restrict__ Wt_lo) {
    int idx = blockIdx.x * 256 + threadIdx.x;   // FOUT * (FIN/8) = 128*32
    if (idx >= FOUT * (FIN / 8)) return;
    int n = idx >> 5, g = idx & 31;
    float x[8];
    #pragma unroll
    for (int i = 0; i < 8; ++i) x[i] = W[(size_t)(g * 8 + i) * FOUT + n];
    uint4 H, L;
    split8(x, H, L);
    reinterpret_cast<uint4*>(Wt_hi)[n * 32 + g] = H;
    reinterpret_cast<uint4*>(Wt_lo)[n * 32 + g] = L;
}

// ---------------- K1: hp = h @ W via split-bf16 MFMA (3 products) ----------------
__global__ __launch_bounds__(256)
void k_hp(const float* __restrict__ h, const ushort* __restrict__ Wt_hi,
          const ushort* __restrict__ Wt_lo, float* __restrict__ hp) {
    __shared__ __align__(16) ushort Ah[64 * 64], Al[64 * 64];    // h tile hi/lo
    __shared__ __align__(16) ushort Bh[128 * 64], Bl[128 * 64];  // Wt tile hi/lo
    const int tid = threadIdx.x, lane = tid & 63, wid = tid >> 6;
    const int wy = wid >> 1, wx = wid & 1;
    const int ibase = blockIdx.x * 64;
    f32x4 z = {0.f, 0.f, 0.f, 0.f};
    f32x4 acc[2][4] = {{z, z, z, z}, {z, z, z, z}};
    for (int kt = 0; kt < 4; ++kt) {
        __syncthreads();
        stage_split<64, 3>(h + (size_t)ibase * FIN + kt * 64, FIN, Ah, Al, tid);
        stage_copy<128, 3>(Wt_hi + kt * 64, FIN, Bh, tid);
        stage_copy<128, 3>(Wt_lo + kt * 64, FIN, Bl, tid);
        __syncthreads();
        #pragma unroll
        for (int pr = 0; pr < 3; ++pr) {
            const ushort* A = (pr == 2) ? Al : Ah;
            const ushort* B = (pr == 1) ? Bl : Bh;
            #pragma unroll
            for (int ks = 0; ks < 2; ++ks) {
                bf16x8 a0 = frag16(A, wy * 32, ks, 3, lane);
                bf16x8 a1 = frag16(A, wy * 32 + 16, ks, 3, lane);
                #pragma unroll
                for (int c = 0; c < 4; ++c) {
                    bf16x8 bb = frag16(B, wx * 64 + c * 16, ks, 3, lane);
                    acc[0][c] = MFMA16(a0, bb, acc[0][c]);
                    acc[1][c] = MFMA16(a1, bb, acc[1][c]);
                }
            }
        }
    }
    #pragma unroll
    for (int r = 0; r < 2; ++r)
        #pragma unroll
        for (int c = 0; c < 4; ++c)
            #pragma unroll
            for (int p = 0; p < 4; ++p) {
                int row = ibase + wy * 32 + r * 16 + (lane >> 4) * 4 + p;
                int col = wx * 64 + c * 16 + (lane & 15);
                hp[(size_t)row * FOUT + col] = acc[r][c][p];
            }
}

// ---------- shared e-tile compute: acc[2][2] over K=128 via 3 split products ----------
__device__ __forceinline__ void etile(const ushort* Ihi, const ushort* Ilo,
                                      const ushort* Jhi, const ushort* Jlo,
                                      int wy, int wx, int lane, f32x4 acc[2][2]) {
    #pragma unroll
    for (int pr = 0; pr < 3; ++pr) {
        const ushort* A = (pr == 2) ? Ilo : Ihi;
        const ushort* B = (pr == 1) ? Jlo : Jhi;
        #pragma unroll
        for (int ks = 0; ks < 4; ++ks) {
            bf16x8 a0 = frag16(A, wy * 32, ks, 4, lane);
            bf16x8 a1 = frag16(A, wy * 32 + 16, ks, 4, lane);
            bf16x8 b0 = frag16(B, wx * 32, ks, 4, lane);
            bf16x8 b1 = frag16(B, wx * 32 + 16, ks, 4, lane);
            acc[0][0] = MFMA16(a0, b0, acc[0][0]);
            acc[0][1] = MFMA16(a0, b1, acc[0][1]);
            acc[1][0] = MFMA16(a1, b0, acc[1][0]);
            acc[1][1] = MFMA16(a1, b1, acc[1][1]);
        }
    }
}

// XCD-aware block decode: batch b pinned to XCD pair {2b, 2b+1} (hp_b fits one 4MB L2)
__device__ __forceinline__ void decode_bid(int bid, int& b, int& strip, int& q) {
    int slot = bid & 7;
    b = slot >> 1;
    int sub = ((bid >> 3) << 1) | (slot & 1);   // 0..255
    strip = sub >> 2;                           // 0..63
    q = sub & 3;                                // 0..3
}

// ---------------- K2: per-column (softmax dim) online max / sum-exp partials ----------------
__global__ __launch_bounds__(256)
void k_colstats(const float* __restrict__ hp, float* __restrict__ m_part,
                float* __restrict__ s_part) {
    __shared__ __align__(16) ushort Jhi[64 * 128], Jlo[64 * 128];
    __shared__ __align__(16) ushort Ihi[64 * 128], Ilo[64 * 128];
    const int tid = threadIdx.x, lane = tid & 63, wid = tid >> 6;
    const int wy = wid >> 1, wx = wid & 1;
    int b, strip, iq;
    decode_bid(blockIdx.x, b, strip, iq);
    const int jbase = strip * 64;
    const float* hpb = hp + (size_t)b * NN * FOUT;
    stage_split<64, 4>(hpb + (size_t)jbase * FOUT, FOUT, Jhi, Jlo, tid);
    float mrun[2] = {-1e30f, -1e30f}, srun[2] = {0.f, 0.f};
    for (int t = 0; t < (NN / NSPLIT) / 64; ++t) {
        int ibase = iq * (NN / NSPLIT) + t * 64;
        __syncthreads();
        stage_split<64, 4>(hpb + (size_t)ibase * FOUT, FOUT, Ihi, Ilo, tid);
        __syncthreads();
        f32x4 zz = {0.f, 0.f, 0.f, 0.f};
        f32x4 acc[2][2] = {{zz, zz}, {zz, zz}};
        etile(Ihi, Ilo, Jhi, Jlo, wy, wx, lane, acc);
        #pragma unroll
        for (int c = 0; c < 2; ++c) {
            float tm = -1e30f;
            #pragma unroll
            for (int r = 0; r < 2; ++r)
                #pragma unroll
                for (int p = 0; p < 4; ++p) {
                    float x = acc[r][c][p];
                    float g = fmaxf(x, ALPHA * x);   // LeakyReLU
                    acc[r][c][p] = g;
                    tm = fmaxf(tm, g);
                }
            tm = fmaxf(tm, __shfl_xor(tm, 16));
            tm = fmaxf(tm, __shfl_xor(tm, 32));
            float mnew = fmaxf(mrun[c], tm);
            float ss = 0.f;
            #pragma unroll
            for (int r = 0; r < 2; ++r)
                #pragma unroll
                for (int p = 0; p < 4; ++p) ss += __expf(acc[r][c][p] - mnew);
            ss += __shfl_xor(ss, 16);
            ss += __shfl_xor(ss, 32);
            srun[c] = srun[c] * __expf(mrun[c] - mnew) + ss;
            mrun[c] = mnew;
        }
    }
    if (lane < 16) {
        int set = ((b * NSPLIT + iq) << 1) + wy;    // 8 partial sets per batch
        #pragma unroll
        for (int c = 0; c < 2; ++c) {
            int j = jbase + wx * 32 + c * 16 + lane;
            m_part[(size_t)set * NN + j] = mrun[c];
            s_part[(size_t)set * NN + j] = srun[c];
        }
    }
}

// ---------------- K2b: merge the 8 column partials ----------------
__global__ void k_merge(const float* __restrict__ m_part, const float* __restrict__ s_part,
                        float* __restrict__ m_fin, float* __restrict__ inv_s) {
    int idx = blockIdx.x * 256 + threadIdx.x;
    if (idx >= BN * NN) return;
    int b = idx >> 12, j = idx & (NN - 1);
    float M = -1e30f;
    #pragma unroll
    for (int k = 0; k < 2 * NSPLIT; ++k)
        M = fmaxf(M, m_part[(size_t)(b * 2 * NSPLIT + k) * NN + j]);
    float S = 0.f;
    #pragma unroll
    for (int k = 0; k < 2 * NSPLIT; ++k) {
        float mp = m_part[(size_t)(b * 2 * NSPLIT + k) * NN + j];
        float sp = s_part[(size_t)(b * 2 * NSPLIT + k) * NN + j];
        S += sp * __expf(mp - M);
    }
    m_fin[idx] = M;
    inv_s[idx] = 1.f / S;
}

// ---------------- K3: row-mass partials ----------------
__global__ __launch_bounds__(256)
void k_rowsum(const float* __restrict__ hp, const float* __restrict__ m_fin,
              const float* __restrict__ inv_s, float* __restrict__ rs_part) {
    __shared__ __align__(16) ushort Ihi[64 * 128], Ilo[64 * 128];
    __shared__ __align__(16) ushort Jhi[64 * 128], Jlo[64 * 128];
    __shared__ float red[64][2];
    const int tid = threadIdx.x, lane = tid & 63, wid = tid >> 6;
    const int wy = wid >> 1, wx = wid & 1;
    int b, strip, jq;
    decode_bid(blockIdx.x, b, strip, jq);
    const int ibase = strip * 64;
    const float* hpb = hp + (size_t)b * NN * FOUT;
    stage_split<64, 4>(hpb + (size_t)ibase * FOUT, FOUT, Ihi, Ilo, tid);
    float rsum[2][4] = {{0.f, 0.f, 0.f, 0.f}, {0.f, 0.f, 0.f, 0.f}};
    for (int t = 0; t < (NN / NSPLIT) / 64; ++t) {
        int jb = jq * (NN / NSPLIT) + t * 64;
        __syncthreads();
        stage_split<64, 4>(hpb + (size_t)jb * FOUT, FOUT, Jhi, Jlo, tid);
        __syncthreads();
        f32x4 zz = {0.f, 0.f, 0.f, 0.f};
        f32x4 acc[2][2] = {{zz, zz}, {zz, zz}};
        etile(Ihi, Ilo, Jhi, Jlo, wy, wx, lane, acc);
        float mj[2], isj[2];
        #pragma unroll
        for (int c = 0; c < 2; ++c) {
            int j = jb + wx * 32 + c * 16 + (lane & 15);
            mj[c] = m_fin[(size_t)b * NN + j];
            isj[c] = inv_s[(size_t)b * NN + j];
        }
        #pragma unroll
        for (int r = 0; r < 2; ++r)
            #pragma unroll
            for (int p = 0; p < 4; ++p) {
                float s0 = 0.f;
                #pragma unroll
                for (int c = 0; c < 2; ++c) {
                    float x = acc[r][c][p];
                    float g = fmaxf(x, ALPHA * x);
                    s0 += __expf(g - mj[c]) * isj[c];
                }
                rsum[r][p] += s0;
            }
    }
    #pragma unroll
    for (int r = 0; r < 2; ++r)
        #pragma unroll
        for (int p = 0; p < 4; ++p) {
            float v = rsum[r][p];
            v += __shfl_xor(v, 1);
            v += __shfl_xor(v, 2);
            v += __shfl_xor(v, 4);
            v += __shfl_xor(v, 8);
            if ((lane & 15) == 0) red[wy * 32 + r * 16 + (lane >> 4) * 4 + p][wx] = v;
        }
    __syncthreads();
    if (tid < 64)
        rs_part[(size_t)(b * NSPLIT + jq) * NN + ibase + tid] = red[tid][0] + red[tid][1];
}

// ---------------- K4: out = hp * row_mass (in place on d_out) ----------------
__global__ void k_scale(const float* __restrict__ rs_part, float* __restrict__ out) {
    int idx = blockIdx.x * 256 + threadIdx.x;      // f4 index
    if (idx >= BN * NN * FOUT / 4) return;
    int row = idx >> 5;                            // b*NN + i
    int b = row >> 12, i = row & (NN - 1);
    float rm = 0.f;
    #pragma unroll
    for (int k = 0; k < NSPLIT; ++k)
        rm += rs_part[(size_t)(b * NSPLIT + k) * NN + i];
    float4 v = reinterpret_cast<float4*>(out)[idx];
    v.x *= rm; v.y *= rm; v.z *= rm; v.w *= rm;
    reinterpret_cast<float4*>(out)[idx] = v;
}

extern "C" void kernel_launch(void* const* d_in, const int* in_sizes, int n_in,
                              void* d_out, int out_size, void* d_ws, size_t ws_size,
                              hipStream_t stream) {
    (void)in_sizes; (void)n_in; (void)out_size; (void)ws_size;
    const float* h = (const float*)d_in[0];
    // d_in[1] = adj (bool) — unused by the reference forward
    const float* W = (const float*)d_in[2];
    float* out = (float*)d_out;                    // doubles as hp buffer
    // workspace layout (~1.6 MB)
    ushort* Wt_hi = (ushort*)d_ws;                               // FOUT*FIN
    ushort* Wt_lo = Wt_hi + FOUT * FIN;                          // FOUT*FIN
    float* m_part = (float*)(Wt_lo + FOUT * FIN);                // BN*8*NN
    float* s_part = m_part + BN * 2 * NSPLIT * NN;
    float* m_fin  = s_part + BN * 2 * NSPLIT * NN;               // BN*NN
    float* inv_s  = m_fin + BN * NN;                             // BN*NN
    float* rs_part = inv_s + BN * NN;                            // BN*NSPLIT*NN

    k_prepW<<<(FOUT * (FIN / 8) + 255) / 256, 256, 0, stream>>>(W, Wt_hi, Wt_lo);
    k_hp<<<BN * NN / 64, 256, 0, stream>>>(h, Wt_hi, Wt_lo, out);
    k_colstats<<<NSPLIT * BN * (NN / 64), 256, 0, stream>>>(out, m_part, s_part);
    k_merge<<<(BN * NN + 255) / 256, 256, 0, stream>>>(m_part, s_part, m_fin, inv_s);
    k_rowsum<<<NSPLIT * BN * (NN / 64), 256, 0, stream>>>(out, m_fin, inv_s, rs_part);
    k_scale<<<(BN * NN * FOUT / 4 + 255) / 256, 256, 0, stream>>>(rs_part, out);
}

// Round 4
// 498.533 us; speedup vs baseline: 1.0018x; 1.0018x over previous
//
#include <hip/hip_runtime.h>
#include <hip/hip_bf16.h>

#define ALPHA 0.2f

constexpr int BN   = 4;
constexpr int NN   = 4096;
constexpr int FIN  = 256;
constexpr int FOUT = 128;
constexpr int NQ   = 8;     // reduction-axis split: 8 quarters of 512 rows (4 tiles of 128)

typedef __attribute__((ext_vector_type(8))) short bf16x8;
typedef __attribute__((ext_vector_type(4))) float f32x4;

#define MFMA16(a, b, c) __builtin_amdgcn_mfma_f32_16x16x32_bf16((a), (b), (c), 0, 0, 0)

// ---------- split one fp32 octet into hi/lo bf16 granules (16B each) ----------
__device__ __forceinline__ void split8(const float* x, uint4& H, uint4& L) {
    ushort hb[8], lb[8];
    #pragma unroll
    for (int i = 0; i < 8; ++i) {
        float xv = x[i];
        __hip_bfloat16 hh = __float2bfloat16(xv);
        float hf = __bfloat162float(hh);
        __hip_bfloat16 lw = __float2bfloat16(xv - hf);
        hb[i] = reinterpret_cast<const ushort&>(hh);
        lb[i] = reinterpret_cast<const ushort&>(lw);
    }
    H = make_uint4((uint)hb[0] | ((uint)hb[1] << 16), (uint)hb[2] | ((uint)hb[3] << 16),
                   (uint)hb[4] | ((uint)hb[5] << 16), (uint)hb[6] | ((uint)hb[7] << 16));
    L = make_uint4((uint)lb[0] | ((uint)lb[1] << 16), (uint)lb[2] | ((uint)lb[3] << 16),
                   (uint)lb[4] | ((uint)lb[5] << 16), (uint)lb[6] | ((uint)lb[7] << 16));
}

// ---------- stage fp32 [ROWS][8<<KGSH] -> swizzled hi/lo bf16 LDS (k_hp only) ----------
template<int ROWS, int KGSH>
__device__ __forceinline__ void stage_split(const float* __restrict__ src, int strideF,
                                            ushort* hi, ushort* lo, int tid) {
    constexpr int KG = 1 << KGSH;
    #pragma unroll
    for (int idx = tid; idx < ROWS * KG; idx += 256) {
        int row = idx >> KGSH, g = idx & (KG - 1);
        const float4* p4 = reinterpret_cast<const float4*>(src + (size_t)row * strideF + g * 8);
        float4 u = p4[0], v = p4[1];
        float x[8] = {u.x, u.y, u.z, u.w, v.x, v.y, v.z, v.w};
        uint4 H, L;
        split8(x, H, L);
        int gran = (row << KGSH) + (g ^ (row & 7));
        reinterpret_cast<uint4*>(hi)[gran] = H;
        reinterpret_cast<uint4*>(lo)[gran] = L;
    }
}

// ---------- stage pre-split bf16 [ROWS][8<<KGSH] -> swizzled LDS (pure copy) ----------
template<int ROWS, int KGSH>
__device__ __forceinline__ void stage_copy(const ushort* __restrict__ src, int strideU,
                                           ushort* dst, int tid) {
    constexpr int KG = 1 << KGSH;
    #pragma unroll
    for (int idx = tid; idx < ROWS * KG; idx += 256) {
        int row = idx >> KGSH, g = idx & (KG - 1);
        uint4 vv = *reinterpret_cast<const uint4*>(src + (size_t)row * strideU + g * 8);
        reinterpret_cast<uint4*>(dst)[(row << KGSH) + (g ^ (row & 7))] = vv;
    }
}

// ---------- fragment read: row (rowbase + lane&15), k-granule ks*4 + lane>>4 ----------
__device__ __forceinline__ bf16x8 frag16(const ushort* s, int rowbase, int kstep, int kgsh, int lane) {
    int r = rowbase + (lane & 15);
    int g = kstep * 4 + (lane >> 4);
    int gran = (r << kgsh) + (g ^ (r & 7));
    return *reinterpret_cast<const bf16x8*>(s + gran * 8);
}

// ---------------- K0: transpose + split W -> Wt_hi/Wt_lo [FOUT][FIN] bf16 ----------------
__global__ void k_prepW(const float* __restrict__ W, ushort* __restrict__ Wt_hi,
                        ushort* __restrict__ Wt_lo) {
    int idx = blockIdx.x * 256 + threadIdx.x;   // FOUT * (FIN/8)
    if (idx >= FOUT * (FIN / 8)) return;
    int n = idx >> 5, g = idx & 31;
    float x[8];
    #pragma unroll
    for (int i = 0; i < 8; ++i) x[i] = W[(size_t)(g * 8 + i) * FOUT + n];
    uint4 H, L;
    split8(x, H, L);
    reinterpret_cast<uint4*>(Wt_hi)[n * 32 + g] = H;
    reinterpret_cast<uint4*>(Wt_lo)[n * 32 + g] = L;
}

// ---------------- K1: hp = h @ W via split-bf16 MFMA; also emits hp_hi/hp_lo ----------------
__global__ __launch_bounds__(256)
void k_hp(const float* __restrict__ h, const ushort* __restrict__ Wt_hi,
          const ushort* __restrict__ Wt_lo, float* __restrict__ hp,
          ushort* __restrict__ hp_hi, ushort* __restrict__ hp_lo) {
    __shared__ __align__(16) ushort Ah[64 * 64], Al[64 * 64];
    __shared__ __align__(16) ushort Bh[128 * 64], Bl[128 * 64];
    const int tid = threadIdx.x, lane = tid & 63, wid = tid >> 6;
    const int wy = wid >> 1, wx = wid & 1;
    const int ibase = blockIdx.x * 64;
    f32x4 z = {0.f, 0.f, 0.f, 0.f};
    f32x4 acc[2][4] = {{z, z, z, z}, {z, z, z, z}};
    for (int kt = 0; kt < 4; ++kt) {
        __syncthreads();
        stage_split<64, 3>(h + (size_t)ibase * FIN + kt * 64, FIN, Ah, Al, tid);
        stage_copy<128, 3>(Wt_hi + kt * 64, FIN, Bh, tid);
        stage_copy<128, 3>(Wt_lo + kt * 64, FIN, Bl, tid);
        __syncthreads();
        #pragma unroll
        for (int pr = 0; pr < 3; ++pr) {
            const ushort* A = (pr == 2) ? Al : Ah;
            const ushort* B = (pr == 1) ? Bl : Bh;
            #pragma unroll
            for (int ks = 0; ks < 2; ++ks) {
                bf16x8 a0 = frag16(A, wy * 32, ks, 3, lane);
                bf16x8 a1 = frag16(A, wy * 32 + 16, ks, 3, lane);
                #pragma unroll
                for (int c = 0; c < 4; ++c) {
                    bf16x8 bb = frag16(B, wx * 64 + c * 16, ks, 3, lane);
                    acc[0][c] = MFMA16(a0, bb, acc[0][c]);
                    acc[1][c] = MFMA16(a1, bb, acc[1][c]);
                }
            }
        }
    }
    #pragma unroll
    for (int r = 0; r < 2; ++r)
        #pragma unroll
        for (int c = 0; c < 4; ++c)
            #pragma unroll
            for (int p = 0; p < 4; ++p) {
                int row = ibase + wy * 32 + r * 16 + (lane >> 4) * 4 + p;
                int col = wx * 64 + c * 16 + (lane & 15);
                float x = acc[r][c][p];
                __hip_bfloat16 hh = __float2bfloat16(x);
                float hf = __bfloat162float(hh);
                __hip_bfloat16 lw = __float2bfloat16(x - hf);
                size_t off = (size_t)row * FOUT + col;
                hp[off] = x;
                hp_hi[off] = reinterpret_cast<const ushort&>(hh);
                hp_lo[off] = reinterpret_cast<const ushort&>(lw);
            }
}

// ---------- 64x64 wave-tile over K=128: 16 reads, 48 MFMA per ks ----------
__device__ __forceinline__ void etile44(const ushort* Ihi, const ushort* Ilo,
                                        const ushort* Jhi, const ushort* Jlo,
                                        int wy, int wx, int lane, f32x4 acc[4][4]) {
    #pragma unroll
    for (int ks = 0; ks < 4; ++ks) {
        bf16x8 aH[4], aL[4], bH[4], bL[4];
        #pragma unroll
        for (int r = 0; r < 4; ++r) {
            aH[r] = frag16(Ihi, wy * 64 + r * 16, ks, 4, lane);
            aL[r] = frag16(Ilo, wy * 64 + r * 16, ks, 4, lane);
        }
        #pragma unroll
        for (int c = 0; c < 4; ++c) {
            bH[c] = frag16(Jhi, wx * 64 + c * 16, ks, 4, lane);
            bL[c] = frag16(Jlo, wx * 64 + c * 16, ks, 4, lane);
        }
        #pragma unroll
        for (int r = 0; r < 4; ++r)
            #pragma unroll
            for (int c = 0; c < 4; ++c) {
                acc[r][c] = MFMA16(aH[r], bH[c], acc[r][c]);
                acc[r][c] = MFMA16(aH[r], bL[c], acc[r][c]);
                acc[r][c] = MFMA16(aL[r], bH[c], acc[r][c]);
            }
    }
}

// XCD-aware decode: batch pinned to an XCD pair; strip 0..31, q 0..7
__device__ __forceinline__ void decode_bid(int bid, int& b, int& strip, int& q) {
    int slot = bid & 7;
    b = slot >> 1;
    int sub = ((bid >> 3) << 1) | (slot & 1);   // 0..255
    strip = sub >> 3;                           // 0..31
    q = sub & 7;                                // 0..7
}

// ---------------- K2: per-column (softmax dim) online max / sum-exp partials ----------------
__global__ __launch_bounds__(256)
void k_colstats(const ushort* __restrict__ hp_hi, const ushort* __restrict__ hp_lo,
                float* __restrict__ m_part, float* __restrict__ s_part) {
    __shared__ __align__(16) ushort Jhi[128 * 128], Jlo[128 * 128];
    __shared__ __align__(16) ushort Ihi[128 * 128], Ilo[128 * 128];
    const int tid = threadIdx.x, lane = tid & 63, wid = tid >> 6;
    const int wy = wid >> 1, wx = wid & 1;
    int b, strip, q;
    decode_bid(blockIdx.x, b, strip, q);
    const int jbase = strip * 128;
    const ushort* hb_hi = hp_hi + (size_t)b * NN * FOUT;
    const ushort* hb_lo = hp_lo + (size_t)b * NN * FOUT;
    stage_copy<128, 4>(hb_hi + (size_t)jbase * FOUT, FOUT, Jhi, tid);
    stage_copy<128, 4>(hb_lo + (size_t)jbase * FOUT, FOUT, Jlo, tid);
    float mrun[4] = {-1e30f, -1e30f, -1e30f, -1e30f};
    float srun[4] = {0.f, 0.f, 0.f, 0.f};
    for (int t = 0; t < 4; ++t) {
        int ibase = q * 512 + t * 128;
        __syncthreads();
        stage_copy<128, 4>(hb_hi + (size_t)ibase * FOUT, FOUT, Ihi, tid);
        stage_copy<128, 4>(hb_lo + (size_t)ibase * FOUT, FOUT, Ilo, tid);
        __syncthreads();
        f32x4 zz = {0.f, 0.f, 0.f, 0.f};
        f32x4 acc[4][4];
        #pragma unroll
        for (int r = 0; r < 4; ++r)
            #pragma unroll
            for (int c = 0; c < 4; ++c) acc[r][c] = zz;
        etile44(Ihi, Ilo, Jhi, Jlo, wy, wx, lane, acc);
        #pragma unroll
        for (int c = 0; c < 4; ++c) {
            float tm = -1e30f;
            #pragma unroll
            for (int r = 0; r < 4; ++r)
                #pragma unroll
                for (int p = 0; p < 4; ++p) {
                    float x = acc[r][c][p];
                    float g = fmaxf(x, ALPHA * x);   // LeakyReLU
                    acc[r][c][p] = g;
                    tm = fmaxf(tm, g);
                }
            tm = fmaxf(tm, __shfl_xor(tm, 16));
            tm = fmaxf(tm, __shfl_xor(tm, 32));
            float mnew = fmaxf(mrun[c], tm);
            float ss = 0.f;
            #pragma unroll
            for (int r = 0; r < 4; ++r)
                #pragma unroll
                for (int p = 0; p < 4; ++p) ss += __expf(acc[r][c][p] - mnew);
            ss += __shfl_xor(ss, 16);
            ss += __shfl_xor(ss, 32);
            srun[c] = srun[c] * __expf(mrun[c] - mnew) + ss;
            mrun[c] = mnew;
        }
    }
    if (lane < 16) {
        int set = b * 16 + q * 2 + wy;   // 16 disjoint i-row sets per batch
        #pragma unroll
        for (int c = 0; c < 4; ++c) {
            int j = jbase + wx * 64 + c * 16 + lane;
            m_part[(size_t)set * NN + j] = mrun[c];
            s_part[(size_t)set * NN + j] = srun[c];
        }
    }
}

// ---------------- K2b: merge the 16 column partials ----------------
__global__ void k_merge(const float* __restrict__ m_part, const float* __restrict__ s_part,
                        float* __restrict__ m_fin, float* __restrict__ inv_s) {
    int idx = blockIdx.x * 256 + threadIdx.x;
    if (idx >= BN * NN) return;
    int b = idx >> 12, j = idx & (NN - 1);
    float M = -1e30f;
    #pragma unroll
    for (int k = 0; k < 16; ++k)
        M = fmaxf(M, m_part[(size_t)(b * 16 + k) * NN + j]);
    float S = 0.f;
    #pragma unroll
    for (int k = 0; k < 16; ++k) {
        float mp = m_part[(size_t)(b * 16 + k) * NN + j];
        float sp = s_part[(size_t)(b * 16 + k) * NN + j];
        S += sp * __expf(mp - M);
    }
    m_fin[idx] = M;
    inv_s[idx] = 1.f / S;
}

// ---------------- K3: row-mass partials ----------------
__global__ __launch_bounds__(256)
void k_rowsum(const ushort* __restrict__ hp_hi, const ushort* __restrict__ hp_lo,
              const float* __restrict__ m_fin, const float* __restrict__ inv_s,
              float* __restrict__ rs_part) {
    __shared__ __align__(16) ushort Ihi[128 * 128], Ilo[128 * 128];
    __shared__ __align__(16) ushort Jhi[128 * 128], Jlo[128 * 128];
    __shared__ float red[128][2];
    const int tid = threadIdx.x, lane = tid & 63, wid = tid >> 6;
    const int wy = wid >> 1, wx = wid & 1;
    int b, strip, jq;
    decode_bid(blockIdx.x, b, strip, jq);
    const int ibase = strip * 128;
    const ushort* hb_hi = hp_hi + (size_t)b * NN * FOUT;
    const ushort* hb_lo = hp_lo + (size_t)b * NN * FOUT;
    stage_copy<128, 4>(hb_hi + (size_t)ibase * FOUT, FOUT, Ihi, tid);
    stage_copy<128, 4>(hb_lo + (size_t)ibase * FOUT, FOUT, Ilo, tid);
    float rsum[4][4] = {};
    for (int t = 0; t < 4; ++t) {
        int jb = jq * 512 + t * 128;
        __syncthreads();
        stage_copy<128, 4>(hb_hi + (size_t)jb * FOUT, FOUT, Jhi, tid);
        stage_copy<128, 4>(hb_lo + (size_t)jb * FOUT, FOUT, Jlo, tid);
        __syncthreads();
        float mj[4], isj[4];
        #pragma unroll
        for (int c = 0; c < 4; ++c) {
            int j = jb + wx * 64 + c * 16 + (lane & 15);
            mj[c] = m_fin[(size_t)b * NN + j];
            isj[c] = inv_s[(size_t)b * NN + j];
        }
        f32x4 zz = {0.f, 0.f, 0.f, 0.f};
        f32x4 acc[4][4];
        #pragma unroll
        for (int r = 0; r < 4; ++r)
            #pragma unroll
            for (int c = 0; c < 4; ++c) acc[r][c] = zz;
        etile44(Ihi, Ilo, Jhi, Jlo, wy, wx, lane, acc);
        #pragma unroll
        for (int r = 0; r < 4; ++r)
            #pragma unroll
            for (int p = 0; p < 4; ++p) {
                float s0 = 0.f;
                #pragma unroll
                for (int c = 0; c < 4; ++c) {
                    float x = acc[r][c][p];
                    float g = fmaxf(x, ALPHA * x);
                    s0 += __expf(g - mj[c]) * isj[c];
                }
                rsum[r][p] += s0;
            }
    }
    #pragma unroll
    for (int r = 0; r < 4; ++r)
        #pragma unroll
        for (int p = 0; p < 4; ++p) {
            float v = rsum[r][p];
            v += __shfl_xor(v, 1);
            v += __shfl_xor(v, 2);
            v += __shfl_xor(v, 4);
            v += __shfl_xor(v, 8);
            if ((lane & 15) == 0) red[wy * 64 + r * 16 + (lane >> 4) * 4 + p][wx] = v;
        }
    __syncthreads();
    if (tid < 128)
        rs_part[(size_t)(b * NQ + jq) * NN + ibase + tid] = red[tid][0] + red[tid][1];
}

// ---------------- K4: out = hp * row_mass (in place on d_out) ----------------
__global__ void k_scale(const float* __restrict__ rs_part, float* __restrict__ out) {
    int idx = blockIdx.x * 256 + threadIdx.x;      // f4 index
    if (idx >= BN * NN * FOUT / 4) return;
    int row = idx >> 5;                            // b*NN + i
    int b = row >> 12, i = row & (NN - 1);
    float rm = 0.f;
    #pragma unroll
    for (int k = 0; k < NQ; ++k)
        rm += rs_part[(size_t)(b * NQ + k) * NN + i];
    float4 v = reinterpret_cast<float4*>(out)[idx];
    v.x *= rm; v.y *= rm; v.z *= rm; v.w *= rm;
    reinterpret_cast<float4*>(out)[idx] = v;
}

extern "C" void kernel_launch(void* const* d_in, const int* in_sizes, int n_in,
                              void* d_out, int out_size, void* d_ws, size_t ws_size,
                              hipStream_t stream) {
    (void)in_sizes; (void)n_in; (void)out_size; (void)ws_size;
    const float* h = (const float*)d_in[0];
    // d_in[1] = adj (bool) — unused by the reference forward
    const float* W = (const float*)d_in[2];
    float* out = (float*)d_out;                    // doubles as hp (fp32)
    // workspace layout (~11.5 MB of ws)
    ushort* hp_hi = (ushort*)d_ws;                               // BN*NN*FOUT
    ushort* hp_lo = hp_hi + (size_t)BN * NN * FOUT;              // BN*NN*FOUT
    ushort* Wt_hi = hp_lo + (size_t)BN * NN * FOUT;              // FOUT*FIN
    ushort* Wt_lo = Wt_hi + FOUT * FIN;                          // FOUT*FIN
    float* m_part = (float*)(Wt_lo + FOUT * FIN);                // BN*16*NN
    float* s_part = m_part + (size_t)BN * 16 * NN;               // BN*16*NN
    float* m_fin  = s_part + (size_t)BN * 16 * NN;               // BN*NN
    float* inv_s  = m_fin + (size_t)BN * NN;                     // BN*NN
    float* rs_part = inv_s + (size_t)BN * NN;                    // BN*NQ*NN

    k_prepW<<<(FOUT * (FIN / 8) + 255) / 256, 256, 0, stream>>>(W, Wt_hi, Wt_lo);
    k_hp<<<BN * NN / 64, 256, 0, stream>>>(h, Wt_hi, Wt_lo, out, hp_hi, hp_lo);
    k_colstats<<<BN * NQ * (NN / 128), 256, 0, stream>>>(hp_hi, hp_lo, m_part, s_part);
    k_merge<<<(BN * NN + 255) / 256, 256, 0, stream>>>(m_part, s_part, m_fin, inv_s);
    k_rowsum<<<BN * NQ * (NN / 128), 256, 0, stream>>>(hp_hi, hp_lo, m_fin, inv_s, rs_part);
    k_scale<<<(BN * NN * FOUT / 4 + 255) / 256, 256, 0, stream>>>(rs_part, out);
}